// Round 4
// baseline (98.545 us; speedup 1.0000x reference)
//
#include <hip/hip_runtime.h>

#define TOK_TOTAL 8192
#define DDIM 512
#define HDIM 256
#define ODIM 2
#define NHEADS 16
#define VOCAB 1024

typedef __attribute__((ext_vector_type(8))) short short8;
typedef __attribute__((ext_vector_type(4))) float f32x4;

__device__ inline ushort f2bf(float f) {           // RNE fp32->bf16
    uint u = __float_as_uint(f);
    uint r = (u + 0x7fffu + ((u >> 16) & 1u)) >> 16;
    return (ushort)r;
}
__device__ inline float bf2f(ushort h) { return __uint_as_float(((uint)h) << 16); }

// ---------------------------------------------------------------- prep ----
// Blocks [0,384): W1/W2 fp32 -> bf16 hi(trunc)/lo(RNE) planes [n][kc][c][ks],
//                 coalesced reads via LDS transpose, coalesced writes.
// Blocks [384,2432): X fp32 -> Xh/Xl bf16 planes, row-major (elementwise).
__global__ __launch_bounds__(256) void mth_prep(
    const float* __restrict__ W1, const float* __restrict__ W2,
    const float* __restrict__ X,
    ushort* __restrict__ W1h, ushort* __restrict__ W1l,
    ushort* __restrict__ W2h, ushort* __restrict__ W2l,
    ushort* __restrict__ Xh, ushort* __restrict__ Xl)
{
    const int b = blockIdx.x, t = threadIdx.x;
    if (b >= 384) {                        // ---- X split, fully coalesced ----
        const size_t q = (size_t)(b - 384) * 256 + t;   // 0..524287, 8 elems each
        const float4 f0 = ((const float4*)X)[q * 2];
        const float4 f1 = ((const float4*)X)[q * 2 + 1];
        const float vv[8] = {f0.x, f0.y, f0.z, f0.w, f1.x, f1.y, f1.z, f1.w};
        short8 hb, lb;
        #pragma unroll
        for (int j = 0; j < 8; ++j) {
            const uint u = __float_as_uint(vv[j]);
            hb[j] = (short)(u >> 16);
            lb[j] = (short)f2bf(vv[j] - __uint_as_float(u & 0xffff0000u));
        }
        ((short8*)Xh)[q] = hb;
        ((short8*)Xl)[q] = lb;
        return;
    }
    __shared__ float s[32][257];
    const float* src;
    ushort *dh, *dl;
    if (b < 256) {
        const int n = b >> 4, kc = b & 15;
        src = W1 + (size_t)(n * 16 + kc) * 8192;
        dh = W1h + (size_t)(n * 16 + kc) * 8192;
        dl = W1l + (size_t)(n * 16 + kc) * 8192;
    } else {
        const int b2 = b - 256, n = b2 >> 3, kc = b2 & 7;
        src = W2 + (size_t)(n * 8 + kc) * 8192;
        dh = W2h + (size_t)(n * 8 + kc) * 8192;
        dl = W2l + (size_t)(n * 8 + kc) * 8192;
    }
    #pragma unroll
    for (int i = 0; i < 8; ++i) {
        const int q = t + i * 256;
        const float4 f = ((const float4*)src)[q];
        const int k = q >> 6, c4 = (q & 63) * 4;
        s[k][c4] = f.x; s[k][c4 + 1] = f.y; s[k][c4 + 2] = f.z; s[k][c4 + 3] = f.w;
    }
    __syncthreads();
    const int g = t & 3;                   // lane->(c,g) for sequential stores
    #pragma unroll
    for (int i = 0; i < 4; ++i) {
        const int c = (t >> 2) + i * 64;
        short8 hb, lb;
        #pragma unroll
        for (int j = 0; j < 8; ++j) {
            const float v = s[g * 8 + j][c];
            const uint u = __float_as_uint(v);
            hb[j] = (short)(u >> 16);
            lb[j] = (short)f2bf(v - __uint_as_float(u & 0xffff0000u));
        }
        *(short8*)(dh + c * 32 + g * 8) = hb;
        *(short8*)(dl + c * 32 + g * 8) = lb;
    }
}

// ------------------------------------------------------------- compact ----
// Also zeroes out[] for invalid tokens (valid tokens are written by mlp).
__global__ __launch_bounds__(256) void mth_compact(
    const int* __restrict__ tasks, const int* __restrict__ lut,
    int* __restrict__ counts, int* __restrict__ lists,
    float* __restrict__ out)
{
    const int tok = blockIdx.x * 256 + threadIdx.x;
    const int l = threadIdx.x & 63;
    const int task = tasks[tok];
    const int h = (task >= 0 && task < VOCAB) ? lut[task] : -1;
    if (h < 0) {
        out[(size_t)tok * 2]     = 0.f;
        out[(size_t)tok * 2 + 1] = 0.f;
    }
    const unsigned long long lt = (1ULL << l) - 1ULL;
    for (int n = 0; n < NHEADS; ++n) {
        const unsigned long long m = __ballot(h == n);
        if (m == 0ULL) continue;
        const int leader = (int)__ffsll((unsigned long long)m) - 1;
        int base = 0;
        if (l == leader) base = atomicAdd(&counts[n], (int)__popcll(m));
        base = __shfl(base, leader);
        if (h == n) lists[n * TOK_TOTAL + base + (int)__popcll(m & lt)] = tok;
    }
}

// --------------------------------------------------------------- mlp2 ----
// Block = 8 waves = 32 tokens x 256 cols; wave w owns cols [w*32, w*32+32).
// A comes straight from pre-split Xh/Xl (no LDS staging, no layer-1 barrier).
// LDS only holds h1 (hi/lo) for the layer-2 k-redistribution. 34 KB/block.
__global__ __launch_bounds__(512) void mth_mlp2(
    const ushort* __restrict__ Xh, const ushort* __restrict__ Xl,
    const int* __restrict__ counts, const int* __restrict__ lists,
    const ushort* __restrict__ W1h, const ushort* __restrict__ W1l,
    const ushort* __restrict__ W2h, const ushort* __restrict__ W2l,
    const float* __restrict__ b1, const float* __restrict__ b2,
    const float* __restrict__ W3, const float* __restrict__ b3,
    float* __restrict__ out)
{
    __shared__ ushort Hh[8][2][64][8];    // 16 KB  [kc2][tf][lane][pos]
    __shared__ ushort Hl[8][2][64][8];    // 16 KB
    __shared__ float  part[8][32][2];     //  2 KB

    const int b = blockIdx.x;
    const int n = ((b & 7) << 1) | ((b >> 3) & 1);  // XCD-clustered heads
    const int tile0 = b >> 4;                        // 0..31, stride 32

    const int tid = threadIdx.x;
    const int w   = tid >> 6;
    const int l   = tid & 63;
    const int r16 = l & 15;
    const int kg  = l >> 4;

    const int cnt = counts[n];
    if (tile0 * 32 >= cnt) return;        // uniform per block

    const int cbase = w * 32;
    const float bias1a = b1[n * HDIM + cbase + r16];
    const float bias1b = b1[n * HDIM + cbase + 16 + r16];
    const float bias2a = b2[n * HDIM + cbase + r16];
    const float bias2b = b2[n * HDIM + cbase + 16 + r16];
    const float2 w3a = *(const float2*)(W3 + (size_t)(n * HDIM + cbase + r16) * 2);
    const float2 w3b = *(const float2*)(W3 + (size_t)(n * HDIM + cbase + 16 + r16) * 2);

    const ushort* w1hn = W1h + (size_t)n * (16 * 8192);
    const ushort* w1ln = W1l + (size_t)n * (16 * 8192);
    const ushort* w2hn = W2h + (size_t)n * (8 * 8192);
    const ushort* w2ln = W2l + (size_t)n * (8 * 8192);
    const int boff = (cbase + r16) * 32 + kg * 8;
    const int listbase = n * TOK_TOTAL;

    for (int T = tile0; T * 32 < cnt; T += 32) {
        const int i0 = min(T * 32 + r16, cnt - 1);
        const int i1 = min(T * 32 + 16 + r16, cnt - 1);
        const size_t row0 = (size_t)lists[listbase + i0] * DDIM + kg * 8;
        const size_t row1 = (size_t)lists[listbase + i1] * DDIM + kg * 8;
        const ushort* xh0 = Xh + row0;
        const ushort* xl0 = Xl + row0;
        const ushort* xh1 = Xh + row1;
        const ushort* xl1 = Xl + row1;

        // ---- layer 1: h1 = relu(X W1 + b1), A direct from global ----
        f32x4 acc[2][2];
        #pragma unroll
        for (int tf = 0; tf < 2; ++tf)
            #pragma unroll
            for (int cf = 0; cf < 2; ++cf) acc[tf][cf] = (f32x4){0.f, 0.f, 0.f, 0.f};

        #pragma unroll 4
        for (int kc = 0; kc < 16; ++kc) {
            const int ab = kc * 32;
            const short8 ah0 = *(const short8*)(xh0 + ab);
            const short8 al0 = *(const short8*)(xl0 + ab);
            const short8 ah1 = *(const short8*)(xh1 + ab);
            const short8 al1 = *(const short8*)(xl1 + ab);
            const int base = kc * 8192 + boff;
            const short8 bh0 = *(const short8*)(w1hn + base);
            const short8 bh1 = *(const short8*)(w1hn + base + 512);
            const short8 bl0 = *(const short8*)(w1ln + base);
            const short8 bl1 = *(const short8*)(w1ln + base + 512);
            acc[0][0] = __builtin_amdgcn_mfma_f32_16x16x32_bf16(ah0, bh0, acc[0][0], 0, 0, 0);
            acc[0][0] = __builtin_amdgcn_mfma_f32_16x16x32_bf16(al0, bh0, acc[0][0], 0, 0, 0);
            acc[0][0] = __builtin_amdgcn_mfma_f32_16x16x32_bf16(ah0, bl0, acc[0][0], 0, 0, 0);
            acc[0][1] = __builtin_amdgcn_mfma_f32_16x16x32_bf16(ah0, bh1, acc[0][1], 0, 0, 0);
            acc[0][1] = __builtin_amdgcn_mfma_f32_16x16x32_bf16(al0, bh1, acc[0][1], 0, 0, 0);
            acc[0][1] = __builtin_amdgcn_mfma_f32_16x16x32_bf16(ah0, bl1, acc[0][1], 0, 0, 0);
            acc[1][0] = __builtin_amdgcn_mfma_f32_16x16x32_bf16(ah1, bh0, acc[1][0], 0, 0, 0);
            acc[1][0] = __builtin_amdgcn_mfma_f32_16x16x32_bf16(al1, bh0, acc[1][0], 0, 0, 0);
            acc[1][0] = __builtin_amdgcn_mfma_f32_16x16x32_bf16(ah1, bl0, acc[1][0], 0, 0, 0);
            acc[1][1] = __builtin_amdgcn_mfma_f32_16x16x32_bf16(ah1, bh1, acc[1][1], 0, 0, 0);
            acc[1][1] = __builtin_amdgcn_mfma_f32_16x16x32_bf16(al1, bh1, acc[1][1], 0, 0, 0);
            acc[1][1] = __builtin_amdgcn_mfma_f32_16x16x32_bf16(ah1, bl1, acc[1][1], 0, 0, 0);
        }

        // ---- h1 -> LDS (trunc-hi / RNE-lo), wave w = layer-2 k-slice w ----
        #pragma unroll
        for (int tf = 0; tf < 2; ++tf) {
            #pragma unroll
            for (int cf = 0; cf < 2; ++cf) {
                const float bias = cf ? bias1b : bias1a;
                const int lhi = (cf * 2 + (r16 >> 3)) * 16 + kg * 4;
                #pragma unroll
                for (int j = 0; j < 4; ++j) {
                    const float v = fmaxf(acc[tf][cf][j] + bias, 0.f);
                    const uint u = __float_as_uint(v);
                    Hh[w][tf][lhi + j][r16 & 7] = (ushort)(u >> 16);
                    Hl[w][tf][lhi + j][r16 & 7] =
                        f2bf(v - __uint_as_float(u & 0xffff0000u));
                }
            }
        }
        __syncthreads();

        // ---- layer 2: h2 = relu(h1 W2 + b2) ----
        f32x4 acc2[2][2];
        #pragma unroll
        for (int tf = 0; tf < 2; ++tf)
            #pragma unroll
            for (int cf = 0; cf < 2; ++cf) acc2[tf][cf] = (f32x4){0.f, 0.f, 0.f, 0.f};

        #pragma unroll 4
        for (int kc = 0; kc < 8; ++kc) {
            const short8 ah0 = *(const short8*)&Hh[kc][0][l][0];
            const short8 al0 = *(const short8*)&Hl[kc][0][l][0];
            const short8 ah1 = *(const short8*)&Hh[kc][1][l][0];
            const short8 al1 = *(const short8*)&Hl[kc][1][l][0];
            const int base = kc * 8192 + boff;
            const short8 bh0 = *(const short8*)(w2hn + base);
            const short8 bh1 = *(const short8*)(w2hn + base + 512);
            const short8 bl0 = *(const short8*)(w2ln + base);
            const short8 bl1 = *(const short8*)(w2ln + base + 512);
            acc2[0][0] = __builtin_amdgcn_mfma_f32_16x16x32_bf16(ah0, bh0, acc2[0][0], 0, 0, 0);
            acc2[0][0] = __builtin_amdgcn_mfma_f32_16x16x32_bf16(al0, bh0, acc2[0][0], 0, 0, 0);
            acc2[0][0] = __builtin_amdgcn_mfma_f32_16x16x32_bf16(ah0, bl0, acc2[0][0], 0, 0, 0);
            acc2[0][1] = __builtin_amdgcn_mfma_f32_16x16x32_bf16(ah0, bh1, acc2[0][1], 0, 0, 0);
            acc2[0][1] = __builtin_amdgcn_mfma_f32_16x16x32_bf16(al0, bh1, acc2[0][1], 0, 0, 0);
            acc2[0][1] = __builtin_amdgcn_mfma_f32_16x16x32_bf16(ah0, bl1, acc2[0][1], 0, 0, 0);
            acc2[1][0] = __builtin_amdgcn_mfma_f32_16x16x32_bf16(ah1, bh0, acc2[1][0], 0, 0, 0);
            acc2[1][0] = __builtin_amdgcn_mfma_f32_16x16x32_bf16(al1, bh0, acc2[1][0], 0, 0, 0);
            acc2[1][0] = __builtin_amdgcn_mfma_f32_16x16x32_bf16(ah1, bl0, acc2[1][0], 0, 0, 0);
            acc2[1][1] = __builtin_amdgcn_mfma_f32_16x16x32_bf16(ah1, bh1, acc2[1][1], 0, 0, 0);
            acc2[1][1] = __builtin_amdgcn_mfma_f32_16x16x32_bf16(al1, bh1, acc2[1][1], 0, 0, 0);
            acc2[1][1] = __builtin_amdgcn_mfma_f32_16x16x32_bf16(ah1, bl1, acc2[1][1], 0, 0, 0);
        }

        // ---- layer 3: partial dot over this wave's 32 cols ----
        float p[2][4][2];
        #pragma unroll
        for (int tf = 0; tf < 2; ++tf)
            #pragma unroll
            for (int j = 0; j < 4; ++j) { p[tf][j][0] = 0.f; p[tf][j][1] = 0.f; }
        #pragma unroll
        for (int tf = 0; tf < 2; ++tf) {
            #pragma unroll
            for (int cf = 0; cf < 2; ++cf) {
                const float bias = cf ? bias2b : bias2a;
                const float w3x = cf ? w3b.x : w3a.x;
                const float w3y = cf ? w3b.y : w3a.y;
                #pragma unroll
                for (int j = 0; j < 4; ++j) {
                    const float v = fmaxf(acc2[tf][cf][j] + bias, 0.f);
                    p[tf][j][0] = fmaf(v, w3x, p[tf][j][0]);
                    p[tf][j][1] = fmaf(v, w3y, p[tf][j][1]);
                }
            }
        }
        #pragma unroll
        for (int off = 8; off >= 1; off >>= 1) {
            #pragma unroll
            for (int tf = 0; tf < 2; ++tf)
                #pragma unroll
                for (int j = 0; j < 4; ++j) {
                    p[tf][j][0] += __shfl_xor(p[tf][j][0], off);
                    p[tf][j][1] += __shfl_xor(p[tf][j][1], off);
                }
        }
        if (r16 == 0) {
            #pragma unroll
            for (int tf = 0; tf < 2; ++tf)
                #pragma unroll
                for (int j = 0; j < 4; ++j) {
                    const int tkn = tf * 16 + kg * 4 + j;
                    part[w][tkn][0] = p[tf][j][0];
                    part[w][tkn][1] = p[tf][j][1];
                }
        }
        __syncthreads();

        if (tid < 64) {
            const int tk = tid >> 1, o = tid & 1;
            if (T * 32 + tk < cnt) {
                float s = 0.f;
                #pragma unroll
                for (int w2 = 0; w2 < 8; ++w2) s += part[w2][tk][o];
                const int tok = lists[listbase + T * 32 + tk];
                out[(size_t)tok * 2 + o] = s + b3[n * 2 + o];
            }
        }
        __syncthreads();
    }
}

// ------------------------------------------- mid path (round-3 kernel) ----
__global__ __launch_bounds__(512) void mth_mlp(
    const float* __restrict__ X, const int* __restrict__ counts,
    const int* __restrict__ lists,
    const ushort* __restrict__ W1h, const ushort* __restrict__ W1l,
    const ushort* __restrict__ W2h, const ushort* __restrict__ W2l,
    const float* __restrict__ b1, const float* __restrict__ b2,
    const float* __restrict__ W3, const float* __restrict__ b3,
    float* __restrict__ out)
{
    __shared__ ushort Ah[16][2][64][8];
    __shared__ ushort Al[16][2][64][8];
    __shared__ ushort Hh[8][2][64][8];
    __shared__ ushort Hl[8][2][64][8];
    __shared__ float  part[8][32][2];

    const int b = blockIdx.x;
    const int n = ((b & 7) << 1) | ((b >> 3) & 1);
    const int tile0 = b >> 4;
    const int tid = threadIdx.x;
    const int w = tid >> 6, l = tid & 63, r16 = l & 15, kg = l >> 4;
    const int cnt = counts[n];
    if (cnt == 0) return;
    const int cbase = w * 32;
    const float bias1a = b1[n * HDIM + cbase + r16];
    const float bias1b = b1[n * HDIM + cbase + 16 + r16];
    const float bias2a = b2[n * HDIM + cbase + r16];
    const float bias2b = b2[n * HDIM + cbase + 16 + r16];
    const float2 w3a = *(const float2*)(W3 + (size_t)(n * HDIM + cbase + r16) * 2);
    const float2 w3b = *(const float2*)(W3 + (size_t)(n * HDIM + cbase + 16 + r16) * 2);
    const ushort* w1hn = W1h + (size_t)n * (16 * 8192);
    const ushort* w1ln = W1l + (size_t)n * (16 * 8192);
    const ushort* w2hn = W2h + (size_t)n * (8 * 8192);
    const ushort* w2ln = W2l + (size_t)n * (8 * 8192);
    const int boff = (cbase + r16) * 32 + kg * 8;
    const int stok = tid >> 4, skc = tid & 15;
    const int stf = stok >> 4, srr = stok & 15;
    const int slsw = (skc & 3) << 2;
    const int listbase = n * TOK_TOTAL;

    for (int T = tile0; T * 32 < cnt; T += 32) {
        {
            const int tokidx = min(T * 32 + stok, cnt - 1);
            const int tok = lists[listbase + tokidx];
            const float* xp = X + (size_t)tok * DDIM + skc * 32;
            #pragma unroll
            for (int g = 0; g < 4; ++g) {
                const float4 f0 = *(const float4*)(xp + g * 8);
                const float4 f1 = *(const float4*)(xp + g * 8 + 4);
                const float vv[8] = {f0.x, f0.y, f0.z, f0.w, f1.x, f1.y, f1.z, f1.w};
                short8 hb, lb;
                #pragma unroll
                for (int j = 0; j < 8; ++j) {
                    const ushort hi = f2bf(vv[j]);
                    hb[j] = (short)hi;
                    lb[j] = (short)f2bf(vv[j] - bf2f(hi));
                }
                const int lane2 = (g * 16 + srr) ^ slsw;
                *(short8*)&Ah[skc][stf][lane2][0] = hb;
                *(short8*)&Al[skc][stf][lane2][0] = lb;
            }
        }
        __syncthreads();
        f32x4 acc[2][2];
        #pragma unroll
        for (int tf = 0; tf < 2; ++tf)
            #pragma unroll
            for (int cf = 0; cf < 2; ++cf) acc[tf][cf] = (f32x4){0.f, 0.f, 0.f, 0.f};
        #pragma unroll 4
        for (int kc = 0; kc < 16; ++kc) {
            const int lr = l ^ ((kc & 3) << 2);
            const short8 ah0 = *(const short8*)&Ah[kc][0][lr][0];
            const short8 al0 = *(const short8*)&Al[kc][0][lr][0];
            const short8 ah1 = *(const short8*)&Ah[kc][1][lr][0];
            const short8 al1 = *(const short8*)&Al[kc][1][lr][0];
            const int base = kc * 8192 + boff;
            const short8 bh0 = *(const short8*)(w1hn + base);
            const short8 bh1 = *(const short8*)(w1hn + base + 512);
            const short8 bl0 = *(const short8*)(w1ln + base);
            const short8 bl1 = *(const short8*)(w1ln + base + 512);
            acc[0][0] = __builtin_amdgcn_mfma_f32_16x16x32_bf16(ah0, bh0, acc[0][0], 0, 0, 0);
            acc[0][0] = __builtin_amdgcn_mfma_f32_16x16x32_bf16(al0, bh0, acc[0][0], 0, 0, 0);
            acc[0][0] = __builtin_amdgcn_mfma_f32_16x16x32_bf16(ah0, bl0, acc[0][0], 0, 0, 0);
            acc[0][1] = __builtin_amdgcn_mfma_f32_16x16x32_bf16(ah0, bh1, acc[0][1], 0, 0, 0);
            acc[0][1] = __builtin_amdgcn_mfma_f32_16x16x32_bf16(al0, bh1, acc[0][1], 0, 0, 0);
            acc[0][1] = __builtin_amdgcn_mfma_f32_16x16x32_bf16(ah0, bl1, acc[0][1], 0, 0, 0);
            acc[1][0] = __builtin_amdgcn_mfma_f32_16x16x32_bf16(ah1, bh0, acc[1][0], 0, 0, 0);
            acc[1][0] = __builtin_amdgcn_mfma_f32_16x16x32_bf16(al1, bh0, acc[1][0], 0, 0, 0);
            acc[1][0] = __builtin_amdgcn_mfma_f32_16x16x32_bf16(ah1, bl0, acc[1][0], 0, 0, 0);
            acc[1][1] = __builtin_amdgcn_mfma_f32_16x16x32_bf16(ah1, bh1, acc[1][1], 0, 0, 0);
            acc[1][1] = __builtin_amdgcn_mfma_f32_16x16x32_bf16(al1, bh1, acc[1][1], 0, 0, 0);
            acc[1][1] = __builtin_amdgcn_mfma_f32_16x16x32_bf16(ah1, bl1, acc[1][1], 0, 0, 0);
        }
        #pragma unroll
        for (int tf = 0; tf < 2; ++tf) {
            #pragma unroll
            for (int cf = 0; cf < 2; ++cf) {
                const float bias = cf ? bias1b : bias1a;
                const int lhi = (cf * 2 + (r16 >> 3)) * 16 + kg * 4;
                #pragma unroll
                for (int j = 0; j < 4; ++j) {
                    const float v = fmaxf(acc[tf][cf][j] + bias, 0.f);
                    const ushort hh = f2bf(v);
                    Hh[w][tf][lhi + j][r16 & 7] = hh;
                    Hl[w][tf][lhi + j][r16 & 7] = f2bf(v - bf2f(hh));
                }
            }
        }
        __syncthreads();
        f32x4 acc2[2][2];
        #pragma unroll
        for (int tf = 0; tf < 2; ++tf)
            #pragma unroll
            for (int cf = 0; cf < 2; ++cf) acc2[tf][cf] = (f32x4){0.f, 0.f, 0.f, 0.f};
        #pragma unroll 4
        for (int kc = 0; kc < 8; ++kc) {
            const short8 ah0 = *(const short8*)&Hh[kc][0][l][0];
            const short8 al0 = *(const short8*)&Hl[kc][0][l][0];
            const short8 ah1 = *(const short8*)&Hh[kc][1][l][0];
            const short8 al1 = *(const short8*)&Hl[kc][1][l][0];
            const int base = kc * 8192 + boff;
            const short8 bh0 = *(const short8*)(w2hn + base);
            const short8 bh1 = *(const short8*)(w2hn + base + 512);
            const short8 bl0 = *(const short8*)(w2ln + base);
            const short8 bl1 = *(const short8*)(w2ln + base + 512);
            acc2[0][0] = __builtin_amdgcn_mfma_f32_16x16x32_bf16(ah0, bh0, acc2[0][0], 0, 0, 0);
            acc2[0][0] = __builtin_amdgcn_mfma_f32_16x16x32_bf16(al0, bh0, acc2[0][0], 0, 0, 0);
            acc2[0][0] = __builtin_amdgcn_mfma_f32_16x16x32_bf16(ah0, bl0, acc2[0][0], 0, 0, 0);
            acc2[0][1] = __builtin_amdgcn_mfma_f32_16x16x32_bf16(ah0, bh1, acc2[0][1], 0, 0, 0);
            acc2[0][1] = __builtin_amdgcn_mfma_f32_16x16x32_bf16(al0, bh1, acc2[0][1], 0, 0, 0);
            acc2[0][1] = __builtin_amdgcn_mfma_f32_16x16x32_bf16(ah0, bl1, acc2[0][1], 0, 0, 0);
            acc2[1][0] = __builtin_amdgcn_mfma_f32_16x16x32_bf16(ah1, bh0, acc2[1][0], 0, 0, 0);
            acc2[1][0] = __builtin_amdgcn_mfma_f32_16x16x32_bf16(al1, bh0, acc2[1][0], 0, 0, 0);
            acc2[1][0] = __builtin_amdgcn_mfma_f32_16x16x32_bf16(ah1, bl0, acc2[1][0], 0, 0, 0);
            acc2[1][1] = __builtin_amdgcn_mfma_f32_16x16x32_bf16(ah1, bh1, acc2[1][1], 0, 0, 0);
            acc2[1][1] = __builtin_amdgcn_mfma_f32_16x16x32_bf16(al1, bh1, acc2[1][1], 0, 0, 0);
            acc2[1][1] = __builtin_amdgcn_mfma_f32_16x16x32_bf16(ah1, bl1, acc2[1][1], 0, 0, 0);
        }
        float p[2][4][2];
        #pragma unroll
        for (int tf = 0; tf < 2; ++tf)
            #pragma unroll
            for (int j = 0; j < 4; ++j) { p[tf][j][0] = 0.f; p[tf][j][1] = 0.f; }
        #pragma unroll
        for (int tf = 0; tf < 2; ++tf) {
            #pragma unroll
            for (int cf = 0; cf < 2; ++cf) {
                const float bias = cf ? bias2b : bias2a;
                const float w3x = cf ? w3b.x : w3a.x;
                const float w3y = cf ? w3b.y : w3a.y;
                #pragma unroll
                for (int j = 0; j < 4; ++j) {
                    const float v = fmaxf(acc2[tf][cf][j] + bias, 0.f);
                    p[tf][j][0] = fmaf(v, w3x, p[tf][j][0]);
                    p[tf][j][1] = fmaf(v, w3y, p[tf][j][1]);
                }
            }
        }
        #pragma unroll
        for (int off = 8; off >= 1; off >>= 1) {
            #pragma unroll
            for (int tf = 0; tf < 2; ++tf)
                #pragma unroll
                for (int j = 0; j < 4; ++j) {
                    p[tf][j][0] += __shfl_xor(p[tf][j][0], off);
                    p[tf][j][1] += __shfl_xor(p[tf][j][1], off);
                }
        }
        if (r16 == 0) {
            #pragma unroll
            for (int tf = 0; tf < 2; ++tf)
                #pragma unroll
                for (int j = 0; j < 4; ++j) {
                    const int tkn = tf * 16 + kg * 4 + j;
                    part[w][tkn][0] = p[tf][j][0];
                    part[w][tkn][1] = p[tf][j][1];
                }
        }
        __syncthreads();
        if (tid < 64) {
            const int tk = tid >> 1, o = tid & 1;
            if (T * 32 + tk < cnt) {
                float s = 0.f;
                #pragma unroll
                for (int w2 = 0; w2 < 8; ++w2) s += part[w2][tk][o];
                const int tok = lists[listbase + T * 32 + tk];
                out[(size_t)tok * 2 + o] = s + b3[n * 2 + o];
            }
        }
        __syncthreads();
    }
}

// ------------------------------------------------- fallback (round 1) ----
#define CHUNKS 16
#define CHUNK (TOK_TOTAL / CHUNKS)
#define TILE 32
#define KB 16

__global__ __launch_bounds__(256) void mth_routed_fp32(
    const float* __restrict__ X, const int* __restrict__ tasks,
    const int* __restrict__ lut,
    const float* __restrict__ W1, const float* __restrict__ b1,
    const float* __restrict__ W2, const float* __restrict__ b2,
    const float* __restrict__ W3, const float* __restrict__ b3,
    float* __restrict__ out)
{
    const int n = blockIdx.x, chnk = blockIdx.y, tid = threadIdx.x;
    const int lane = tid & 63, wv = tid >> 6, tx = tid & 31, ty = tid >> 5;
    __shared__ int s_list[CHUNK];
    __shared__ int s_cnt[8];
    __shared__ __align__(16) float s_x[KB][TILE];
    __shared__ __align__(16) float s_w[KB][HDIM];
    __shared__ __align__(16) float s_h[HDIM][TILE];
    const int base = chnk * CHUNK;
    int mytok[2], mypre[2], myseg[2]; bool mymatch[2];
    #pragma unroll
    for (int i = 0; i < 2; ++i) {
        const int tok = base + i * 256 + tid;
        const int task = tasks[tok];
        const int hidx = (task >= 0 && task < VOCAB) ? lut[task] : -1;
        const bool match = (hidx == n);
        const unsigned long long mask = __ballot(match);
        mytok[i] = tok; mymatch[i] = match;
        mypre[i] = __popcll(mask & ((1ULL << lane) - 1ULL));
        myseg[i] = i * 4 + wv;
        if (lane == 0) s_cnt[i * 4 + wv] = (int)__popcll(mask);
    }
    __syncthreads();
    int total = 0; int myoff[2] = {0, 0};
    #pragma unroll
    for (int s2 = 0; s2 < 8; ++s2) {
        if (s2 == myseg[0]) myoff[0] = total;
        if (s2 == myseg[1]) myoff[1] = total;
        total += s_cnt[s2];
    }
    #pragma unroll
    for (int i = 0; i < 2; ++i)
        if (mymatch[i]) s_list[myoff[i] + mypre[i]] = mytok[i];
    __syncthreads();
    const int ntok = total;
    if (ntok == 0) return;
    float bias1[8], bias2[8];
    #pragma unroll
    for (int j = 0; j < 8; ++j) {
        bias1[j] = b1[n * HDIM + tx * 8 + j];
        bias2[j] = b2[n * HDIM + tx * 8 + j];
    }
    float w3v[16];
    #pragma unroll
    for (int j = 0; j < 16; ++j) w3v[j] = W3[n * HDIM * ODIM + tx * 8 * ODIM + j];
    const float b3v0 = b3[n * ODIM + 0], b3v1 = b3[n * ODIM + 1];
    const float* W1n = W1 + (size_t)n * DDIM * HDIM;
    const float* W2n = W2 + (size_t)n * HDIM * HDIM;
    for (int ts = 0; ts < ntok; ts += TILE) {
        const int m = min(TILE, ntok - ts);
        float acc[4][8];
        #pragma unroll
        for (int t = 0; t < 4; ++t)
            #pragma unroll
            for (int j = 0; j < 8; ++j) acc[t][j] = 0.f;
        for (int kc = 0; kc < DDIM / KB; ++kc) {
            const float4* src = (const float4*)(W1n + kc * KB * HDIM);
            float4* dst = (float4*)s_w;
            #pragma unroll
            for (int p = 0; p < 4; ++p) dst[tid + p * 256] = src[tid + p * 256];
            #pragma unroll
            for (int p = 0; p < 2; ++p) {
                const int e = tid + p * 256;
                const int dd = e >> 5, t = e & 31;
                float v = 0.f;
                if (t < m) v = X[(size_t)s_list[ts + t] * DDIM + kc * KB + dd];
                s_x[dd][t] = v;
            }
            __syncthreads();
            #pragma unroll
            for (int dd = 0; dd < KB; ++dd) {
                const float4 xa = *(const float4*)&s_x[dd][ty * 4];
                const float4 wa = *(const float4*)&s_w[dd][tx * 8];
                const float4 wb = *(const float4*)&s_w[dd][tx * 8 + 4];
                const float xs[4] = {xa.x, xa.y, xa.z, xa.w};
                const float ws[8] = {wa.x, wa.y, wa.z, wa.w, wb.x, wb.y, wb.z, wb.w};
                #pragma unroll
                for (int t = 0; t < 4; ++t)
                    #pragma unroll
                    for (int j = 0; j < 8; ++j) acc[t][j] = fmaf(xs[t], ws[j], acc[t][j]);
            }
            __syncthreads();
        }
        #pragma unroll
        for (int j = 0; j < 8; ++j) {
            float4 v;
            v.x = fmaxf(acc[0][j] + bias1[j], 0.f);
            v.y = fmaxf(acc[1][j] + bias1[j], 0.f);
            v.z = fmaxf(acc[2][j] + bias1[j], 0.f);
            v.w = fmaxf(acc[3][j] + bias1[j], 0.f);
            *(float4*)&s_h[tx * 8 + j][ty * 4] = v;
        }
        __syncthreads();
        float acc2[4][8];
        #pragma unroll
        for (int t = 0; t < 4; ++t)
            #pragma unroll
            for (int j = 0; j < 8; ++j) acc2[t][j] = 0.f;
        for (int kc = 0; kc < HDIM / KB; ++kc) {
            const float4* src = (const float4*)(W2n + kc * KB * HDIM);
            float4* dst = (float4*)s_w;
            #pragma unroll
            for (int p = 0; p < 4; ++p) dst[tid + p * 256] = src[tid + p * 256];
            __syncthreads();
            #pragma unroll
            for (int dd = 0; dd < KB; ++dd) {
                const int k = kc * KB + dd;
                const float4 xa = *(const float4*)&s_h[k][ty * 4];
                const float4 wa = *(const float4*)&s_w[dd][tx * 8];
                const float4 wb = *(const float4*)&s_w[dd][tx * 8 + 4];
                const float xs[4] = {xa.x, xa.y, xa.z, xa.w};
                const float ws[8] = {wa.x, wa.y, wa.z, wa.w, wb.x, wb.y, wb.z, wb.w};
                #pragma unroll
                for (int t = 0; t < 4; ++t)
                    #pragma unroll
                    for (int j = 0; j < 8; ++j) acc2[t][j] = fmaf(xs[t], ws[j], acc2[t][j]);
            }
            __syncthreads();
        }
        float p0[4] = {0.f, 0.f, 0.f, 0.f}, p1[4] = {0.f, 0.f, 0.f, 0.f};
        #pragma unroll
        for (int t = 0; t < 4; ++t)
            #pragma unroll
            for (int j = 0; j < 8; ++j) {
                const float v = fmaxf(acc2[t][j] + bias2[j], 0.f);
                p0[t] = fmaf(v, w3v[j * 2 + 0], p0[t]);
                p1[t] = fmaf(v, w3v[j * 2 + 1], p1[t]);
            }
        #pragma unroll
        for (int off = 16; off > 0; off >>= 1)
            #pragma unroll
            for (int t = 0; t < 4; ++t) {
                p0[t] += __shfl_xor(p0[t], off);
                p1[t] += __shfl_xor(p1[t], off);
            }
        if (tx == 0) {
            #pragma unroll
            for (int t = 0; t < 4; ++t) {
                const int ti = ty * 4 + t;
                if (ti < m) {
                    const int tok = s_list[ts + ti];
                    out[tok * ODIM + 0] = p0[t] + b3v0;
                    out[tok * ODIM + 1] = p1[t] + b3v1;
                }
            }
        }
        __syncthreads();
    }
}

// -------------------------------------------------------------- launch ----
extern "C" void kernel_launch(void* const* d_in, const int* in_sizes, int n_in,
                              void* d_out, int out_size, void* d_ws, size_t ws_size,
                              hipStream_t stream) {
    (void)in_sizes; (void)n_in;
    const float* X     = (const float*)d_in[0];
    const int*   tasks = (const int*)d_in[1];
    const int*   lut   = (const int*)d_in[2];
    const float* W1    = (const float*)d_in[3];
    const float* b1    = (const float*)d_in[4];
    const float* W2    = (const float*)d_in[5];
    const float* b2    = (const float*)d_in[6];
    const float* W3    = (const float*)d_in[7];
    const float* b3    = (const float*)d_in[8];
    float* out = (float*)d_out;

    const size_t OFF_COUNTS = 0;
    const size_t OFF_LISTS  = 64;
    const size_t OFF_W1H    = OFF_LISTS + (size_t)NHEADS * TOK_TOTAL * 4;
    const size_t NW1        = (size_t)NHEADS * DDIM * HDIM;   // 2M elems
    const size_t NW2        = (size_t)NHEADS * HDIM * HDIM;   // 1M elems
    const size_t NX         = (size_t)TOK_TOTAL * DDIM;       // 4M elems
    const size_t OFF_W1L    = OFF_W1H + NW1 * 2;
    const size_t OFF_W2H    = OFF_W1L + NW1 * 2;
    const size_t OFF_W2L    = OFF_W2H + NW2 * 2;
    const size_t OFF_XH     = OFF_W2L + NW2 * 2;
    const size_t OFF_XL     = OFF_XH + NX * 2;
    const size_t NEED_FULL  = OFF_XL + NX * 2;                // ~28.5 MB
    const size_t NEED_MID   = OFF_XH;                         // ~13.1 MB

    if (ws_size < NEED_MID) {
        hipMemsetAsync(out, 0, (size_t)out_size * sizeof(float), stream);
        dim3 grid(NHEADS, CHUNKS);
        mth_routed_fp32<<<grid, 256, 0, stream>>>(X, tasks, lut, W1, b1, W2, b2, W3, b3, out);
        return;
    }

    char* ws = (char*)d_ws;
    int*    counts = (int*)(ws + OFF_COUNTS);
    int*    lists  = (int*)(ws + OFF_LISTS);
    ushort* W1h    = (ushort*)(ws + OFF_W1H);
    ushort* W1l    = (ushort*)(ws + OFF_W1L);
    ushort* W2h    = (ushort*)(ws + OFF_W2H);
    ushort* W2l    = (ushort*)(ws + OFF_W2L);
    ushort* Xh     = (ushort*)(ws + OFF_XH);
    ushort* Xl     = (ushort*)(ws + OFF_XL);

    hipMemsetAsync(counts, 0, 16 * sizeof(int), stream);

    if (ws_size >= NEED_FULL) {
        mth_prep<<<2432, 256, 0, stream>>>(W1, W2, X, W1h, W1l, W2h, W2l, Xh, Xl);
        mth_compact<<<TOK_TOTAL / 256, 256, 0, stream>>>(tasks, lut, counts, lists, out);
        mth_mlp2<<<512, 512, 0, stream>>>(Xh, Xl, counts, lists, W1h, W1l, W2h, W2l,
                                          b1, b2, W3, b3, out);
    } else {
        mth_prep<<<384, 256, 0, stream>>>(W1, W2, X, W1h, W1l, W2h, W2l, Xh, Xl);
        mth_compact<<<TOK_TOTAL / 256, 256, 0, stream>>>(tasks, lut, counts, lists, out);
        mth_mlp<<<512, 512, 0, stream>>>(X, counts, lists, W1h, W1l, W2h, W2l,
                                         b1, b2, W3, b3, out);
    }
}

// Round 5
// 65.864 us; speedup vs baseline: 1.4962x; 1.4962x over previous
//
#include <hip/hip_runtime.h>

#define TOK_TOTAL 8192
#define DDIM 512
#define HDIM 256
#define ODIM 2
#define NHEADS 16
#define VOCAB 1024

typedef __attribute__((ext_vector_type(8))) short short8;
typedef __attribute__((ext_vector_type(4))) float f32x4;

__device__ inline ushort f2bf(float f) {           // RNE fp32->bf16
    uint u = __float_as_uint(f);
    uint r = (u + 0x7fffu + ((u >> 16) & 1u)) >> 16;
    return (ushort)r;
}
__device__ inline float bf2f(ushort h) { return __uint_as_float(((uint)h) << 16); }

// ---------------------------------------------------------- prep+route ----
// Blocks [0,384): W1/W2 fp32 -> bf16 hi(trunc)/lo(RNE) planes [n][kc][c][ks].
// Blocks [384,416): deterministic routing (no global atomics, no memset):
//   block i handles tokens [256i,256i+256); prefix over earlier chunks via
//   LDS-atomic histogram; in-chunk rank via per-wave ballots. Block 31
//   writes total counts. Invalid tokens' outputs zeroed here.
__global__ __launch_bounds__(256) void mth_prep_route(
    const float* __restrict__ W1, const float* __restrict__ W2,
    const int* __restrict__ tasks, const int* __restrict__ lut,
    ushort* __restrict__ W1h, ushort* __restrict__ W1l,
    ushort* __restrict__ W2h, ushort* __restrict__ W2l,
    int* __restrict__ counts, int* __restrict__ lists,
    float* __restrict__ out)
{
    const int b = blockIdx.x, t = threadIdx.x;

    if (b < 384) {                       // ---------------- W split ----------
        __shared__ float s[32][257];
        const float* src;
        ushort *dh, *dl;
        if (b < 256) {
            const int n = b >> 4, kc = b & 15;
            src = W1 + (size_t)(n * 16 + kc) * 8192;
            dh = W1h + (size_t)(n * 16 + kc) * 8192;
            dl = W1l + (size_t)(n * 16 + kc) * 8192;
        } else {
            const int b2 = b - 256, n = b2 >> 3, kc = b2 & 7;
            src = W2 + (size_t)(n * 8 + kc) * 8192;
            dh = W2h + (size_t)(n * 8 + kc) * 8192;
            dl = W2l + (size_t)(n * 8 + kc) * 8192;
        }
        #pragma unroll
        for (int i = 0; i < 8; ++i) {
            const int q = t + i * 256;
            const float4 f = ((const float4*)src)[q];
            const int k = q >> 6, c4 = (q & 63) * 4;
            s[k][c4] = f.x; s[k][c4 + 1] = f.y; s[k][c4 + 2] = f.z; s[k][c4 + 3] = f.w;
        }
        __syncthreads();
        const int g = t & 3;
        #pragma unroll
        for (int i = 0; i < 4; ++i) {
            const int c = (t >> 2) + i * 64;
            short8 hb, lb;
            #pragma unroll
            for (int j = 0; j < 8; ++j) {
                const float v = s[g * 8 + j][c];
                const uint u = __float_as_uint(v);
                hb[j] = (short)(u >> 16);
                lb[j] = (short)f2bf(v - __uint_as_float(u & 0xffff0000u));
            }
            *(short8*)(dh + c * 32 + g * 8) = hb;
            *(short8*)(dl + c * 32 + g * 8) = lb;
        }
        return;
    }

    // ---------------- routing ----------------
    const int i = b - 384;               // chunk 0..31
    __shared__ int hist[16];             // counts in chunks < i
    __shared__ int wcnt[4][16];          // per-wave counts in own chunk
    if (t < 16) hist[t] = 0;
    __syncthreads();
    for (int q = t; q < i * 256; q += 256) {
        const int task = tasks[q];
        const int h = (task >= 0 && task < VOCAB) ? lut[task] : -1;
        if (h >= 0) atomicAdd(&hist[h], 1);
    }
    const int tok = i * 256 + t;
    const int task = tasks[tok];
    const int h = (task >= 0 && task < VOCAB) ? lut[task] : -1;
    if (h < 0) {
        out[(size_t)tok * 2]     = 0.f;
        out[(size_t)tok * 2 + 1] = 0.f;
    }
    const int w = t >> 6, l = t & 63;
    const unsigned long long lt = (1ULL << l) - 1ULL;
    int pre = 0;
    #pragma unroll
    for (int n = 0; n < NHEADS; ++n) {
        const unsigned long long m = __ballot(h == n);
        if (h == n) pre = (int)__popcll(m & lt);
        if (l == 0) wcnt[w][n] = (int)__popcll(m);
    }
    __syncthreads();
    if (h >= 0) {
        int off = hist[h];
        for (int w2 = 0; w2 < w; ++w2) off += wcnt[w2][h];
        lists[h * TOK_TOTAL + off + pre] = tok;
    }
    if (i == 31 && t < 16) {
        int tot = hist[t];
        #pragma unroll
        for (int w2 = 0; w2 < 4; ++w2) tot += wcnt[w2][t];
        counts[t] = tot;
    }
}

// --------------------------------------------------------------- mlp3 ----
// 16-token tiles, 4 waves/block (256 thr); wave w owns cols [64w,64w+64).
// X staged fp32->hi/lo into LDS in fragment-major order (conflict-free
// contiguous b128 reads); B streamed from L2 (weights in [n][kc][c][ks]).
__global__ __launch_bounds__(256) void mth_mlp3(
    const float* __restrict__ X, const int* __restrict__ counts,
    const int* __restrict__ lists,
    const ushort* __restrict__ W1h, const ushort* __restrict__ W1l,
    const ushort* __restrict__ W2h, const ushort* __restrict__ W2l,
    const float* __restrict__ b1, const float* __restrict__ b2,
    const float* __restrict__ W3, const float* __restrict__ b3,
    float* __restrict__ out)
{
    __shared__ __align__(16) ushort Ah[16][64][8];   // 16 KB  [kc][lane][e]
    __shared__ __align__(16) ushort Al[16][64][8];   // 16 KB
    __shared__ __align__(16) ushort Hh[8][64][8];    //  8 KB  [kc2][lane][e]
    __shared__ __align__(16) ushort Hl[8][64][8];    //  8 KB
    __shared__ float part[4][16][2];                 //  0.5 KB

    const int b = blockIdx.x;
    const int n = ((b & 7) << 1) | ((b >> 3) & 1);   // XCD-clustered heads
    const int tile0 = b >> 4;                         // 0..63, stride 64

    const int tid = threadIdx.x;
    const int w   = tid >> 6;
    const int l   = tid & 63;
    const int r16 = l & 15;
    const int kg  = l >> 4;

    const int cnt = counts[n];
    const int listbase = n * TOK_TOTAL;
    const int cbase = w * 64;

    float bias1[4], bias2[4];
    float2 w3v[4];
    int boff[4];
    #pragma unroll
    for (int cf = 0; cf < 4; ++cf) {
        const int col = cbase + cf * 16 + r16;
        bias1[cf] = b1[n * HDIM + col];
        bias2[cf] = b2[n * HDIM + col];
        w3v[cf]   = *(const float2*)(W3 + (size_t)(n * HDIM + col) * 2);
        boff[cf]  = col * 32 + kg * 8;
    }
    const ushort* w1hn = W1h + (size_t)n * (16 * 8192);
    const ushort* w1ln = W1l + (size_t)n * (16 * 8192);
    const ushort* w2hn = W2h + (size_t)n * (8 * 8192);
    const ushort* w2ln = W2l + (size_t)n * (8 * 8192);

    const int sr = tid & 15;     // stage: token row
    const int sc = tid >> 4;     // stage: kc chunk

    for (int T = tile0; T * 16 < cnt; T += 64) {
        // ---- stage A: 16 rows of X, fp32 coalesced -> hi/lo fragments ----
        {
            const int tokidx = min(T * 16 + sr, cnt - 1);
            const int tok = lists[listbase + tokidx];
            const float* xp = X + (size_t)tok * DDIM + sc * 32;
            #pragma unroll
            for (int g = 0; g < 4; ++g) {
                const float4 f0 = *(const float4*)(xp + g * 8);
                const float4 f1 = *(const float4*)(xp + g * 8 + 4);
                const float vv[8] = {f0.x, f0.y, f0.z, f0.w, f1.x, f1.y, f1.z, f1.w};
                short8 hb, lb;
                #pragma unroll
                for (int j = 0; j < 8; ++j) {
                    const uint u = __float_as_uint(vv[j]);
                    hb[j] = (short)(u >> 16);
                    lb[j] = (short)f2bf(vv[j] - __uint_as_float(u & 0xffff0000u));
                }
                *(short8*)&Ah[sc][g * 16 + sr][0] = hb;
                *(short8*)&Al[sc][g * 16 + sr][0] = lb;
            }
        }
        __syncthreads();

        // ---- layer 1: h1 = relu(X W1 + b1) ----
        f32x4 acc[4];
        #pragma unroll
        for (int cf = 0; cf < 4; ++cf) acc[cf] = (f32x4){0.f, 0.f, 0.f, 0.f};

        #pragma unroll 4
        for (int kc = 0; kc < 16; ++kc) {
            const short8 ah = *(const short8*)&Ah[kc][l][0];
            const short8 al = *(const short8*)&Al[kc][l][0];
            const int base = kc * 8192;
            #pragma unroll
            for (int cf = 0; cf < 4; ++cf) {
                const short8 bh = *(const short8*)(w1hn + base + boff[cf]);
                const short8 bl = *(const short8*)(w1ln + base + boff[cf]);
                acc[cf] = __builtin_amdgcn_mfma_f32_16x16x32_bf16(ah, bh, acc[cf], 0, 0, 0);
                acc[cf] = __builtin_amdgcn_mfma_f32_16x16x32_bf16(al, bh, acc[cf], 0, 0, 0);
                acc[cf] = __builtin_amdgcn_mfma_f32_16x16x32_bf16(ah, bl, acc[cf], 0, 0, 0);
            }
        }

        // ---- h1 -> LDS fragments (wave w owns kc2 in {2w, 2w+1}) ----
        #pragma unroll
        for (int cf = 0; cf < 4; ++cf) {
            const int kc2 = 2 * w + (cf >> 1);
            const int lp  = ((cf & 1) * 2 + (r16 >> 3)) * 16;
            const int e   = r16 & 7;
            #pragma unroll
            for (int j = 0; j < 4; ++j) {
                const float v = fmaxf(acc[cf][j] + bias1[cf], 0.f);
                const uint u = __float_as_uint(v);
                Hh[kc2][lp + kg * 4 + j][e] = (ushort)(u >> 16);
                Hl[kc2][lp + kg * 4 + j][e] =
                    f2bf(v - __uint_as_float(u & 0xffff0000u));
            }
        }
        __syncthreads();

        // ---- layer 2: h2 = relu(h1 W2 + b2) ----
        f32x4 acc2[4];
        #pragma unroll
        for (int cf = 0; cf < 4; ++cf) acc2[cf] = (f32x4){0.f, 0.f, 0.f, 0.f};

        #pragma unroll 4
        for (int kc = 0; kc < 8; ++kc) {
            const short8 ah = *(const short8*)&Hh[kc][l][0];
            const short8 al = *(const short8*)&Hl[kc][l][0];
            const int base = kc * 8192;
            #pragma unroll
            for (int cf = 0; cf < 4; ++cf) {
                const short8 bh = *(const short8*)(w2hn + base + boff[cf]);
                const short8 bl = *(const short8*)(w2ln + base + boff[cf]);
                acc2[cf] = __builtin_amdgcn_mfma_f32_16x16x32_bf16(ah, bh, acc2[cf], 0, 0, 0);
                acc2[cf] = __builtin_amdgcn_mfma_f32_16x16x32_bf16(al, bh, acc2[cf], 0, 0, 0);
                acc2[cf] = __builtin_amdgcn_mfma_f32_16x16x32_bf16(ah, bl, acc2[cf], 0, 0, 0);
            }
        }

        // ---- layer 3: partial dot over this wave's 64 cols ----
        float p[4][2];
        #pragma unroll
        for (int j = 0; j < 4; ++j) { p[j][0] = 0.f; p[j][1] = 0.f; }
        #pragma unroll
        for (int cf = 0; cf < 4; ++cf) {
            #pragma unroll
            for (int j = 0; j < 4; ++j) {
                const float v = fmaxf(acc2[cf][j] + bias2[cf], 0.f);
                p[j][0] = fmaf(v, w3v[cf].x, p[j][0]);
                p[j][1] = fmaf(v, w3v[cf].y, p[j][1]);
            }
        }
        #pragma unroll
        for (int off = 8; off >= 1; off >>= 1) {
            #pragma unroll
            for (int j = 0; j < 4; ++j) {
                p[j][0] += __shfl_xor(p[j][0], off);
                p[j][1] += __shfl_xor(p[j][1], off);
            }
        }
        if (r16 == 0) {
            #pragma unroll
            for (int j = 0; j < 4; ++j) {
                part[w][kg * 4 + j][0] = p[j][0];
                part[w][kg * 4 + j][1] = p[j][1];
            }
        }
        __syncthreads();

        if (tid < 32) {
            const int tk = tid >> 1, o = tid & 1;
            if (T * 16 + tk < cnt) {
                const float s = part[0][tk][o] + part[1][tk][o] +
                                part[2][tk][o] + part[3][tk][o];
                const int tok = lists[listbase + T * 16 + tk];
                out[(size_t)tok * 2 + o] = s + b3[n * 2 + o];
            }
        }
        __syncthreads();
    }
}

// ------------------------------------------------- fallback (round 1) ----
#define CHUNKS 16
#define CHUNK (TOK_TOTAL / CHUNKS)
#define TILE 32
#define KB 16

__global__ __launch_bounds__(256) void mth_routed_fp32(
    const float* __restrict__ X, const int* __restrict__ tasks,
    const int* __restrict__ lut,
    const float* __restrict__ W1, const float* __restrict__ b1,
    const float* __restrict__ W2, const float* __restrict__ b2,
    const float* __restrict__ W3, const float* __restrict__ b3,
    float* __restrict__ out)
{
    const int n = blockIdx.x, chnk = blockIdx.y, tid = threadIdx.x;
    const int lane = tid & 63, wv = tid >> 6, tx = tid & 31, ty = tid >> 5;
    __shared__ int s_list[CHUNK];
    __shared__ int s_cnt[8];
    __shared__ __align__(16) float s_x[KB][TILE];
    __shared__ __align__(16) float s_w[KB][HDIM];
    __shared__ __align__(16) float s_h[HDIM][TILE];
    const int base = chnk * CHUNK;
    int mytok[2], mypre[2], myseg[2]; bool mymatch[2];
    #pragma unroll
    for (int i = 0; i < 2; ++i) {
        const int tok = base + i * 256 + tid;
        const int task = tasks[tok];
        const int hidx = (task >= 0 && task < VOCAB) ? lut[task] : -1;
        const bool match = (hidx == n);
        const unsigned long long mask = __ballot(match);
        mytok[i] = tok; mymatch[i] = match;
        mypre[i] = __popcll(mask & ((1ULL << lane) - 1ULL));
        myseg[i] = i * 4 + wv;
        if (lane == 0) s_cnt[i * 4 + wv] = (int)__popcll(mask);
    }
    __syncthreads();
    int total = 0; int myoff[2] = {0, 0};
    #pragma unroll
    for (int s2 = 0; s2 < 8; ++s2) {
        if (s2 == myseg[0]) myoff[0] = total;
        if (s2 == myseg[1]) myoff[1] = total;
        total += s_cnt[s2];
    }
    #pragma unroll
    for (int i = 0; i < 2; ++i)
        if (mymatch[i]) s_list[myoff[i] + mypre[i]] = mytok[i];
    __syncthreads();
    const int ntok = total;
    if (ntok == 0) return;
    float bias1[8], bias2[8];
    #pragma unroll
    for (int j = 0; j < 8; ++j) {
        bias1[j] = b1[n * HDIM + tx * 8 + j];
        bias2[j] = b2[n * HDIM + tx * 8 + j];
    }
    float w3v[16];
    #pragma unroll
    for (int j = 0; j < 16; ++j) w3v[j] = W3[n * HDIM * ODIM + tx * 8 * ODIM + j];
    const float b3v0 = b3[n * ODIM + 0], b3v1 = b3[n * ODIM + 1];
    const float* W1n = W1 + (size_t)n * DDIM * HDIM;
    const float* W2n = W2 + (size_t)n * HDIM * HDIM;
    for (int ts = 0; ts < ntok; ts += TILE) {
        const int m = min(TILE, ntok - ts);
        float acc[4][8];
        #pragma unroll
        for (int t = 0; t < 4; ++t)
            #pragma unroll
            for (int j = 0; j < 8; ++j) acc[t][j] = 0.f;
        for (int kc = 0; kc < DDIM / KB; ++kc) {
            const float4* src = (const float4*)(W1n + kc * KB * HDIM);
            float4* dst = (float4*)s_w;
            #pragma unroll
            for (int p = 0; p < 4; ++p) dst[tid + p * 256] = src[tid + p * 256];
            #pragma unroll
            for (int p = 0; p < 2; ++p) {
                const int e = tid + p * 256;
                const int dd = e >> 5, t = e & 31;
                float v = 0.f;
                if (t < m) v = X[(size_t)s_list[ts + t] * DDIM + kc * KB + dd];
                s_x[dd][t] = v;
            }
            __syncthreads();
            #pragma unroll
            for (int dd = 0; dd < KB; ++dd) {
                const float4 xa = *(const float4*)&s_x[dd][ty * 4];
                const float4 wa = *(const float4*)&s_w[dd][tx * 8];
                const float4 wb = *(const float4*)&s_w[dd][tx * 8 + 4];
                const float xs[4] = {xa.x, xa.y, xa.z, xa.w};
                const float ws[8] = {wa.x, wa.y, wa.z, wa.w, wb.x, wb.y, wb.z, wb.w};
                #pragma unroll
                for (int t = 0; t < 4; ++t)
                    #pragma unroll
                    for (int j = 0; j < 8; ++j) acc[t][j] = fmaf(xs[t], ws[j], acc[t][j]);
            }
            __syncthreads();
        }
        #pragma unroll
        for (int j = 0; j < 8; ++j) {
            float4 v;
            v.x = fmaxf(acc[0][j] + bias1[j], 0.f);
            v.y = fmaxf(acc[1][j] + bias1[j], 0.f);
            v.z = fmaxf(acc[2][j] + bias1[j], 0.f);
            v.w = fmaxf(acc[3][j] + bias1[j], 0.f);
            *(float4*)&s_h[tx * 8 + j][ty * 4] = v;
        }
        __syncthreads();
        float acc2[4][8];
        #pragma unroll
        for (int t = 0; t < 4; ++t)
            #pragma unroll
            for (int j = 0; j < 8; ++j) acc2[t][j] = 0.f;
        for (int kc = 0; kc < HDIM / KB; ++kc) {
            const float4* src = (const float4*)(W2n + kc * KB * HDIM);
            float4* dst = (float4*)s_w;
            #pragma unroll
            for (int p = 0; p < 4; ++p) dst[tid + p * 256] = src[tid + p * 256];
            __syncthreads();
            #pragma unroll
            for (int dd = 0; dd < KB; ++dd) {
                const int k = kc * KB + dd;
                const float4 xa = *(const float4*)&s_h[k][ty * 4];
                const float4 wa = *(const float4*)&s_w[dd][tx * 8];
                const float4 wb = *(const float4*)&s_w[dd][tx * 8 + 4];
                const float xs[4] = {xa.x, xa.y, xa.z, xa.w};
                const float ws[8] = {wa.x, wa.y, wa.z, wa.w, wb.x, wb.y, wb.z, wb.w};
                #pragma unroll
                for (int t = 0; t < 4; ++t)
                    #pragma unroll
                    for (int j = 0; j < 8; ++j) acc2[t][j] = fmaf(xs[t], ws[j], acc2[t][j]);
            }
            __syncthreads();
        }
        float p0[4] = {0.f, 0.f, 0.f, 0.f}, p1[4] = {0.f, 0.f, 0.f, 0.f};
        #pragma unroll
        for (int t = 0; t < 4; ++t)
            #pragma unroll
            for (int j = 0; j < 8; ++j) {
                const float v = fmaxf(acc2[t][j] + bias2[j], 0.f);
                p0[t] = fmaf(v, w3v[j * 2 + 0], p0[t]);
                p1[t] = fmaf(v, w3v[j * 2 + 1], p1[t]);
            }
        #pragma unroll
        for (int off = 16; off > 0; off >>= 1)
            #pragma unroll
            for (int t = 0; t < 4; ++t) {
                p0[t] += __shfl_xor(p0[t], off);
                p1[t] += __shfl_xor(p1[t], off);
            }
        if (tx == 0) {
            #pragma unroll
            for (int t = 0; t < 4; ++t) {
                const int ti = ty * 4 + t;
                if (ti < m) {
                    const int tok = s_list[ts + ti];
                    out[tok * ODIM + 0] = p0[t] + b3v0;
                    out[tok * ODIM + 1] = p1[t] + b3v1;
                }
            }
        }
        __syncthreads();
    }
}

// -------------------------------------------------------------- launch ----
extern "C" void kernel_launch(void* const* d_in, const int* in_sizes, int n_in,
                              void* d_out, int out_size, void* d_ws, size_t ws_size,
                              hipStream_t stream) {
    (void)in_sizes; (void)n_in;
    const float* X     = (const float*)d_in[0];
    const int*   tasks = (const int*)d_in[1];
    const int*   lut   = (const int*)d_in[2];
    const float* W1    = (const float*)d_in[3];
    const float* b1    = (const float*)d_in[4];
    const float* W2    = (const float*)d_in[5];
    const float* b2    = (const float*)d_in[6];
    const float* W3    = (const float*)d_in[7];
    const float* b3    = (const float*)d_in[8];
    float* out = (float*)d_out;

    const size_t OFF_COUNTS = 0;
    const size_t OFF_LISTS  = 64;
    const size_t OFF_W1H    = OFF_LISTS + (size_t)NHEADS * TOK_TOTAL * 4;
    const size_t NW1        = (size_t)NHEADS * DDIM * HDIM;   // 2M elems
    const size_t NW2        = (size_t)NHEADS * HDIM * HDIM;   // 1M elems
    const size_t OFF_W1L    = OFF_W1H + NW1 * 2;
    const size_t OFF_W2H    = OFF_W1L + NW1 * 2;
    const size_t OFF_W2L    = OFF_W2H + NW2 * 2;
    const size_t NEED       = OFF_W2L + NW2 * 2;              // ~13.1 MB

    if (ws_size < NEED) {
        hipMemsetAsync(out, 0, (size_t)out_size * sizeof(float), stream);
        dim3 grid(NHEADS, CHUNKS);
        mth_routed_fp32<<<grid, 256, 0, stream>>>(X, tasks, lut, W1, b1, W2, b2, W3, b3, out);
        return;
    }

    char* ws = (char*)d_ws;
    int*    counts = (int*)(ws + OFF_COUNTS);
    int*    lists  = (int*)(ws + OFF_LISTS);
    ushort* W1h    = (ushort*)(ws + OFF_W1H);
    ushort* W1l    = (ushort*)(ws + OFF_W1L);
    ushort* W2h    = (ushort*)(ws + OFF_W2H);
    ushort* W2l    = (ushort*)(ws + OFF_W2L);

    mth_prep_route<<<416, 256, 0, stream>>>(W1, W2, tasks, lut,
                                            W1h, W1l, W2h, W2l,
                                            counts, lists, out);
    mth_mlp3<<<1024, 256, 0, stream>>>(X, counts, lists, W1h, W1l, W2h, W2l,
                                       b1, b2, W3, b3, out);
}

// Round 6
// 33.861 us; speedup vs baseline: 2.9103x; 1.9451x over previous
//
#include <hip/hip_runtime.h>

#define TOK_TOTAL 8192
#define DDIM 512
#define HDIM 256
#define ODIM 2
#define NHEADS 16
#define VOCAB 1024

typedef __attribute__((ext_vector_type(8))) short short8;
typedef __attribute__((ext_vector_type(4))) float f32x4;
typedef __attribute__((ext_vector_type(4))) unsigned short ushort4v;

__device__ inline ushort f2bf(float f) {           // RNE fp32->bf16
    uint u = __float_as_uint(f);
    uint r = (u + 0x7fffu + ((u >> 16) & 1u)) >> 16;
    return (ushort)r;
}
__device__ inline float bf2f(ushort h) { return __uint_as_float(((uint)h) << 16); }

// ---------------------------------------------------------- prep+route ----
// Blocks [0,384): W1/W2 fp32 -> single bf16(RNE) plane per (n,kc) in
//   LANE-MONOTONIC fragment order: slot = cg*512 + lane*8 + j holds element
//   (k = kc*32 + (lane>>4)*8 + j, c = cg*16 + (lane&15)). A wave's B-frag
//   load is then one contiguous 1KB read (base + lane*16B).
// Blocks [384,416): deterministic routing (no global atomics, no memset).
__global__ __launch_bounds__(256) void mth_prep_route(
    const float* __restrict__ W1, const float* __restrict__ W2,
    const int* __restrict__ tasks, const int* __restrict__ lut,
    ushort* __restrict__ W1h, ushort* __restrict__ W2h,
    int* __restrict__ counts, int* __restrict__ lists,
    float* __restrict__ out)
{
    const int b = blockIdx.x, t = threadIdx.x;

    if (b < 384) {                       // ---------------- W split ----------
        __shared__ float s[32][257];
        const float* src;
        ushort* dh;
        if (b < 256) {
            const int n = b >> 4, kc = b & 15;
            src = W1 + (size_t)(n * 16 + kc) * 8192;
            dh  = W1h + (size_t)(n * 16 + kc) * 8192;
        } else {
            const int b2 = b - 256, n = b2 >> 3, kc = b2 & 7;
            src = W2 + (size_t)(n * 8 + kc) * 8192;
            dh  = W2h + (size_t)(n * 8 + kc) * 8192;
        }
        #pragma unroll
        for (int i = 0; i < 8; ++i) {
            const int q = t + i * 256;
            const float4 f = ((const float4*)src)[q];
            const int k = q >> 6, c4 = (q & 63) * 4;
            s[k][c4] = f.x; s[k][c4 + 1] = f.y; s[k][c4 + 2] = f.z; s[k][c4 + 3] = f.w;
        }
        __syncthreads();
        #pragma unroll
        for (int i = 0; i < 4; ++i) {
            const int s8 = t + i * 256;          // short8 slot, monotonic
            const int lidx = s8 & 63;
            const int c = (s8 >> 6) * 16 + (lidx & 15);
            const int kw = (lidx >> 4) * 8;
            short8 hb;
            #pragma unroll
            for (int j = 0; j < 8; ++j) hb[j] = (short)f2bf(s[kw + j][c]);
            *(short8*)(dh + (size_t)s8 * 8) = hb;
        }
        return;
    }

    // ---------------- routing ----------------
    const int i = b - 384;               // chunk 0..31
    __shared__ int hist[16];
    __shared__ int wcnt[4][16];
    if (t < 16) hist[t] = 0;
    __syncthreads();
    for (int q = t; q < i * 256; q += 256) {
        const int task = tasks[q];
        const int h = (task >= 0 && task < VOCAB) ? lut[task] : -1;
        if (h >= 0) atomicAdd(&hist[h], 1);
    }
    const int tok = i * 256 + t;
    const int task = tasks[tok];
    const int h = (task >= 0 && task < VOCAB) ? lut[task] : -1;
    if (h < 0) {
        out[(size_t)tok * 2]     = 0.f;
        out[(size_t)tok * 2 + 1] = 0.f;
    }
    const int w = t >> 6, l = t & 63;
    const unsigned long long lt = (1ULL << l) - 1ULL;
    int pre = 0;
    #pragma unroll
    for (int n = 0; n < NHEADS; ++n) {
        const unsigned long long m = __ballot(h == n);
        if (h == n) pre = (int)__popcll(m & lt);
        if (l == 0) wcnt[w][n] = (int)__popcll(m);
    }
    __syncthreads();
    if (h >= 0) {
        int off = hist[h];
        for (int w2 = 0; w2 < w; ++w2) off += wcnt[w2][h];
        lists[h * TOK_TOTAL + off + pre] = tok;
    }
    if (i == 31 && t < 16) {
        int tot = hist[t];
        #pragma unroll
        for (int w2 = 0; w2 < 4; ++w2) tot += wcnt[w2][t];
        counts[t] = tot;
    }
}

// --------------------------------------------------------------- mlp4 ----
// 16-token tiles, 4 waves/block; wave w owns cols [64w, 64w+64).
// B: lane-monotonic fragment planes (1KB contiguous wave loads), bf16 hi only.
// A: X staged fp32 -> hi/lo LDS fragments (XOR-swizzled by kc for writes).
__global__ __launch_bounds__(256) void mth_mlp4(
    const float* __restrict__ X, const int* __restrict__ counts,
    const int* __restrict__ lists,
    const ushort* __restrict__ W1h, const ushort* __restrict__ W2h,
    const float* __restrict__ b1, const float* __restrict__ b2,
    const float* __restrict__ W3, const float* __restrict__ b3,
    float* __restrict__ out)
{
    __shared__ __align__(16) ushort Ah[16][64][8];   // 16 KB
    __shared__ __align__(16) ushort Al[16][64][8];   // 16 KB
    __shared__ __align__(16) ushort Hh[8][64][8];    //  8 KB
    __shared__ __align__(16) ushort Hl[8][64][8];    //  8 KB
    __shared__ float part[4][16][2];

    const int b = blockIdx.x;
    const int n = ((b & 7) << 1) | ((b >> 3) & 1);   // XCD-clustered heads
    const int tile0 = b >> 4;                         // 0..63, stride 64

    const int tid = threadIdx.x;
    const int w   = tid >> 6;
    const int l   = tid & 63;
    const int r16 = l & 15;
    const int kg  = l >> 4;

    const int cnt = counts[n];
    const int listbase = n * TOK_TOTAL;

    float bias1[4], bias2[4];
    float2 w3v[4];
    #pragma unroll
    for (int cf = 0; cf < 4; ++cf) {
        const int col = w * 64 + cf * 16 + r16;
        bias1[cf] = b1[n * HDIM + col];
        bias2[cf] = b2[n * HDIM + col];
        w3v[cf]   = *(const float2*)(W3 + (size_t)(n * HDIM + col) * 2);
    }
    const ushort* w1hn = W1h + (size_t)n * (16 * 8192);
    const ushort* w2hn = W2h + (size_t)n * (8 * 8192);
    const int le8 = l * 8;                            // lane element offset

    for (int T = tile0; T * 16 < cnt; T += 64) {
        // ---- stage: 16 X rows (fp32, contiguous 1KB wave reads) -> frags --
        #pragma unroll
        for (int p = 0; p < 8; ++p) {
            const int q   = tid + p * 256;            // float4 slot 0..2047
            const int row = q >> 7;
            const int f4  = q & 127;
            const int tokidx = min(T * 16 + row, cnt - 1);
            const int tok = lists[listbase + tokidx];
            const float4 f = *(const float4*)(X + (size_t)tok * DDIM + f4 * 4);
            const int kc  = f4 >> 3;
            const int kgw = (f4 >> 1) & 3;
            const int j0  = (f4 & 1) * 4;
            const int ln2 = (kgw * 16 + row) ^ (kc & 7);
            ushort4v hv, lv;
            const float vv[4] = {f.x, f.y, f.z, f.w};
            #pragma unroll
            for (int e = 0; e < 4; ++e) {
                const uint u = __float_as_uint(vv[e]);
                hv[e] = (ushort)(u >> 16);
                lv[e] = f2bf(vv[e] - __uint_as_float(u & 0xffff0000u));
            }
            *(ushort4v*)&Ah[kc][ln2][j0] = hv;
            *(ushort4v*)&Al[kc][ln2][j0] = lv;
        }
        __syncthreads();

        // ---- layer 1: h1 = relu(X W1 + b1) ----
        f32x4 acc[4];
        #pragma unroll
        for (int cf = 0; cf < 4; ++cf) acc[cf] = (f32x4){0.f, 0.f, 0.f, 0.f};

        #pragma unroll 4
        for (int kc = 0; kc < 16; ++kc) {
            const int ls = l ^ (kc & 7);
            const short8 ah = *(const short8*)&Ah[kc][ls][0];
            const short8 al = *(const short8*)&Al[kc][ls][0];
            const ushort* bp = w1hn + kc * 8192 + le8;
            #pragma unroll
            for (int cf = 0; cf < 4; ++cf) {
                const short8 bh = *(const short8*)(bp + (w * 4 + cf) * 512);
                acc[cf] = __builtin_amdgcn_mfma_f32_16x16x32_bf16(ah, bh, acc[cf], 0, 0, 0);
                acc[cf] = __builtin_amdgcn_mfma_f32_16x16x32_bf16(al, bh, acc[cf], 0, 0, 0);
            }
        }

        // ---- h1 -> LDS fragments (hi/lo), wave w owns kc2 in {2w,2w+1} ----
        #pragma unroll
        for (int cf = 0; cf < 4; ++cf) {
            const int kc2 = 2 * w + (cf >> 1);
            const int lp  = ((cf & 1) * 2 + (r16 >> 3)) * 16;
            const int e   = r16 & 7;
            #pragma unroll
            for (int j = 0; j < 4; ++j) {
                const float v = fmaxf(acc[cf][j] + bias1[cf], 0.f);
                const uint u = __float_as_uint(v);
                Hh[kc2][lp + kg * 4 + j][e] = (ushort)(u >> 16);
                Hl[kc2][lp + kg * 4 + j][e] =
                    f2bf(v - __uint_as_float(u & 0xffff0000u));
            }
        }
        __syncthreads();

        // ---- layer 2: h2 = relu(h1 W2 + b2) ----
        f32x4 acc2[4];
        #pragma unroll
        for (int cf = 0; cf < 4; ++cf) acc2[cf] = (f32x4){0.f, 0.f, 0.f, 0.f};

        #pragma unroll 4
        for (int kc = 0; kc < 8; ++kc) {
            const short8 ah = *(const short8*)&Hh[kc][l][0];
            const short8 al = *(const short8*)&Hl[kc][l][0];
            const ushort* bp = w2hn + kc * 8192 + le8;
            #pragma unroll
            for (int cf = 0; cf < 4; ++cf) {
                const short8 bh = *(const short8*)(bp + (w * 4 + cf) * 512);
                acc2[cf] = __builtin_amdgcn_mfma_f32_16x16x32_bf16(ah, bh, acc2[cf], 0, 0, 0);
                acc2[cf] = __builtin_amdgcn_mfma_f32_16x16x32_bf16(al, bh, acc2[cf], 0, 0, 0);
            }
        }

        // ---- layer 3: partial dot over this wave's 64 cols ----
        float p[4][2];
        #pragma unroll
        for (int j = 0; j < 4; ++j) { p[j][0] = 0.f; p[j][1] = 0.f; }
        #pragma unroll
        for (int cf = 0; cf < 4; ++cf) {
            #pragma unroll
            for (int j = 0; j < 4; ++j) {
                const float v = fmaxf(acc2[cf][j] + bias2[cf], 0.f);
                p[j][0] = fmaf(v, w3v[cf].x, p[j][0]);
                p[j][1] = fmaf(v, w3v[cf].y, p[j][1]);
            }
        }
        #pragma unroll
        for (int off = 8; off >= 1; off >>= 1) {
            #pragma unroll
            for (int j = 0; j < 4; ++j) {
                p[j][0] += __shfl_xor(p[j][0], off);
                p[j][1] += __shfl_xor(p[j][1], off);
            }
        }
        if (r16 == 0) {
            #pragma unroll
            for (int j = 0; j < 4; ++j) {
                part[w][kg * 4 + j][0] = p[j][0];
                part[w][kg * 4 + j][1] = p[j][1];
            }
        }
        __syncthreads();

        if (tid < 32) {
            const int tk = tid >> 1, o = tid & 1;
            if (T * 16 + tk < cnt) {
                const float s = part[0][tk][o] + part[1][tk][o] +
                                part[2][tk][o] + part[3][tk][o];
                const int tok = lists[listbase + T * 16 + tk];
                out[(size_t)tok * 2 + o] = s + b3[n * 2 + o];
            }
        }
        __syncthreads();
    }
}

// ------------------------------------------------- fallback (round 1) ----
#define CHUNKS 16
#define CHUNK (TOK_TOTAL / CHUNKS)
#define TILE 32
#define KB 16

__global__ __launch_bounds__(256) void mth_routed_fp32(
    const float* __restrict__ X, const int* __restrict__ tasks,
    const int* __restrict__ lut,
    const float* __restrict__ W1, const float* __restrict__ b1,
    const float* __restrict__ W2, const float* __restrict__ b2,
    const float* __restrict__ W3, const float* __restrict__ b3,
    float* __restrict__ out)
{
    const int n = blockIdx.x, chnk = blockIdx.y, tid = threadIdx.x;
    const int lane = tid & 63, wv = tid >> 6, tx = tid & 31, ty = tid >> 5;
    __shared__ int s_list[CHUNK];
    __shared__ int s_cnt[8];
    __shared__ __align__(16) float s_x[KB][TILE];
    __shared__ __align__(16) float s_w[KB][HDIM];
    __shared__ __align__(16) float s_h[HDIM][TILE];
    const int base = chnk * CHUNK;
    int mytok[2], mypre[2], myseg[2]; bool mymatch[2];
    #pragma unroll
    for (int i = 0; i < 2; ++i) {
        const int tok = base + i * 256 + tid;
        const int task = tasks[tok];
        const int hidx = (task >= 0 && task < VOCAB) ? lut[task] : -1;
        const bool match = (hidx == n);
        const unsigned long long mask = __ballot(match);
        mytok[i] = tok; mymatch[i] = match;
        mypre[i] = __popcll(mask & ((1ULL << lane) - 1ULL));
        myseg[i] = i * 4 + wv;
        if (lane == 0) s_cnt[i * 4 + wv] = (int)__popcll(mask);
    }
    __syncthreads();
    int total = 0; int myoff[2] = {0, 0};
    #pragma unroll
    for (int s2 = 0; s2 < 8; ++s2) {
        if (s2 == myseg[0]) myoff[0] = total;
        if (s2 == myseg[1]) myoff[1] = total;
        total += s_cnt[s2];
    }
    #pragma unroll
    for (int i = 0; i < 2; ++i)
        if (mymatch[i]) s_list[myoff[i] + mypre[i]] = mytok[i];
    __syncthreads();
    const int ntok = total;
    if (ntok == 0) return;
    float bias1[8], bias2[8];
    #pragma unroll
    for (int j = 0; j < 8; ++j) {
        bias1[j] = b1[n * HDIM + tx * 8 + j];
        bias2[j] = b2[n * HDIM + tx * 8 + j];
    }
    float w3v[16];
    #pragma unroll
    for (int j = 0; j < 16; ++j) w3v[j] = W3[n * HDIM * ODIM + tx * 8 * ODIM + j];
    const float b3v0 = b3[n * ODIM + 0], b3v1 = b3[n * ODIM + 1];
    const float* W1n = W1 + (size_t)n * DDIM * HDIM;
    const float* W2n = W2 + (size_t)n * HDIM * HDIM;
    for (int ts = 0; ts < ntok; ts += TILE) {
        const int m = min(TILE, ntok - ts);
        float acc[4][8];
        #pragma unroll
        for (int t = 0; t < 4; ++t)
            #pragma unroll
            for (int j = 0; j < 8; ++j) acc[t][j] = 0.f;
        for (int kc = 0; kc < DDIM / KB; ++kc) {
            const float4* src = (const float4*)(W1n + kc * KB * HDIM);
            float4* dst = (float4*)s_w;
            #pragma unroll
            for (int p = 0; p < 4; ++p) dst[tid + p * 256] = src[tid + p * 256];
            #pragma unroll
            for (int p = 0; p < 2; ++p) {
                const int e = tid + p * 256;
                const int dd = e >> 5, t = e & 31;
                float v = 0.f;
                if (t < m) v = X[(size_t)s_list[ts + t] * DDIM + kc * KB + dd];
                s_x[dd][t] = v;
            }
            __syncthreads();
            #pragma unroll
            for (int dd = 0; dd < KB; ++dd) {
                const float4 xa = *(const float4*)&s_x[dd][ty * 4];
                const float4 wa = *(const float4*)&s_w[dd][tx * 8];
                const float4 wb = *(const float4*)&s_w[dd][tx * 8 + 4];
                const float xs[4] = {xa.x, xa.y, xa.z, xa.w};
                const float ws[8] = {wa.x, wa.y, wa.z, wa.w, wb.x, wb.y, wb.z, wb.w};
                #pragma unroll
                for (int t = 0; t < 4; ++t)
                    #pragma unroll
                    for (int j = 0; j < 8; ++j) acc[t][j] = fmaf(xs[t], ws[j], acc[t][j]);
            }
            __syncthreads();
        }
        #pragma unroll
        for (int j = 0; j < 8; ++j) {
            float4 v;
            v.x = fmaxf(acc[0][j] + bias1[j], 0.f);
            v.y = fmaxf(acc[1][j] + bias1[j], 0.f);
            v.z = fmaxf(acc[2][j] + bias1[j], 0.f);
            v.w = fmaxf(acc[3][j] + bias1[j], 0.f);
            *(float4*)&s_h[tx * 8 + j][ty * 4] = v;
        }
        __syncthreads();
        float acc2[4][8];
        #pragma unroll
        for (int t = 0; t < 4; ++t)
            #pragma unroll
            for (int j = 0; j < 8; ++j) acc2[t][j] = 0.f;
        for (int kc = 0; kc < HDIM / KB; ++kc) {
            const float4* src = (const float4*)(W2n + kc * KB * HDIM);
            float4* dst = (float4*)s_w;
            #pragma unroll
            for (int p = 0; p < 4; ++p) dst[tid + p * 256] = src[tid + p * 256];
            __syncthreads();
            #pragma unroll
            for (int dd = 0; dd < KB; ++dd) {
                const int k = kc * KB + dd;
                const float4 xa = *(const float4*)&s_h[k][ty * 4];
                const float4 wa = *(const float4*)&s_w[dd][tx * 8];
                const float4 wb = *(const float4*)&s_w[dd][tx * 8 + 4];
                const float xs[4] = {xa.x, xa.y, xa.z, xa.w};
                const float ws[8] = {wa.x, wa.y, wa.z, wa.w, wb.x, wb.y, wb.z, wb.w};
                #pragma unroll
                for (int t = 0; t < 4; ++t)
                    #pragma unroll
                    for (int j = 0; j < 8; ++j) acc2[t][j] = fmaf(xs[t], ws[j], acc2[t][j]);
            }
            __syncthreads();
        }
        float p0[4] = {0.f, 0.f, 0.f, 0.f}, p1[4] = {0.f, 0.f, 0.f, 0.f};
        #pragma unroll
        for (int t = 0; t < 4; ++t)
            #pragma unroll
            for (int j = 0; j < 8; ++j) {
                const float v = fmaxf(acc2[t][j] + bias2[j], 0.f);
                p0[t] = fmaf(v, w3v[j * 2 + 0], p0[t]);
                p1[t] = fmaf(v, w3v[j * 2 + 1], p1[t]);
            }
        #pragma unroll
        for (int off = 16; off > 0; off >>= 1)
            #pragma unroll
            for (int t = 0; t < 4; ++t) {
                p0[t] += __shfl_xor(p0[t], off);
                p1[t] += __shfl_xor(p1[t], off);
            }
        if (tx == 0) {
            #pragma unroll
            for (int t = 0; t < 4; ++t) {
                const int ti = ty * 4 + t;
                if (ti < m) {
                    const int tok = s_list[ts + ti];
                    out[tok * ODIM + 0] = p0[t] + b3v0;
                    out[tok * ODIM + 1] = p1[t] + b3v1;
                }
            }
        }
        __syncthreads();
    }
}

// -------------------------------------------------------------- launch ----
extern "C" void kernel_launch(void* const* d_in, const int* in_sizes, int n_in,
                              void* d_out, int out_size, void* d_ws, size_t ws_size,
                              hipStream_t stream) {
    (void)in_sizes; (void)n_in;
    const float* X     = (const float*)d_in[0];
    const int*   tasks = (const int*)d_in[1];
    const int*   lut   = (const int*)d_in[2];
    const float* W1    = (const float*)d_in[3];
    const float* b1    = (const float*)d_in[4];
    const float* W2    = (const float*)d_in[5];
    const float* b2    = (const float*)d_in[6];
    const float* W3    = (const float*)d_in[7];
    const float* b3    = (const float*)d_in[8];
    float* out = (float*)d_out;

    const size_t OFF_COUNTS = 0;
    const size_t OFF_LISTS  = 64;
    const size_t OFF_W1H    = OFF_LISTS + (size_t)NHEADS * TOK_TOTAL * 4;
    const size_t NW1        = (size_t)NHEADS * DDIM * HDIM;   // 2M elems
    const size_t NW2        = (size_t)NHEADS * HDIM * HDIM;   // 1M elems
    const size_t OFF_W2H    = OFF_W1H + NW1 * 2;
    const size_t NEED       = OFF_W2H + NW2 * 2;              // ~6.8 MB

    if (ws_size < NEED) {
        hipMemsetAsync(out, 0, (size_t)out_size * sizeof(float), stream);
        dim3 grid(NHEADS, CHUNKS);
        mth_routed_fp32<<<grid, 256, 0, stream>>>(X, tasks, lut, W1, b1, W2, b2, W3, b3, out);
        return;
    }

    char* ws = (char*)d_ws;
    int*    counts = (int*)(ws + OFF_COUNTS);
    int*    lists  = (int*)(ws + OFF_LISTS);
    ushort* W1h    = (ushort*)(ws + OFF_W1H);
    ushort* W2h    = (ushort*)(ws + OFF_W2H);

    mth_prep_route<<<416, 256, 0, stream>>>(W1, W2, tasks, lut,
                                            W1h, W2h, counts, lists, out);
    mth_mlp4<<<1024, 256, 0, stream>>>(X, counts, lists, W1h, W2h,
                                       b1, b2, W3, b3, out);
}